// Round 15
// baseline (168.484 us; speedup 1.0000x reference)
//
#include <hip/hip_runtime.h>
#include <hip/hip_bf16.h>

#define B_ROWS 65536
#define NA 128
#define D_OUT 1024
#define VBS 128
#define NCHUNK (B_ROWS / VBS)   // 512

typedef __attribute__((ext_vector_type(8))) short bf16x8s;
typedef __attribute__((ext_vector_type(4))) float f32x4;
typedef __attribute__((ext_vector_type(2))) float f32x2;
typedef __attribute__((ext_vector_type(4))) unsigned short u16x4;
typedef __attribute__((ext_vector_type(8))) unsigned short u16x8;

static __device__ __forceinline__ short f2bf(float f) {
    unsigned u = __builtin_bit_cast(unsigned, f);
    u = u + 0x7FFFu + ((u >> 16) & 1u);   // round-to-nearest-even to bf16
    return (short)(u >> 16);
}
static __device__ __forceinline__ float bf2f(unsigned short h) {
    unsigned u = ((unsigned)h) << 16;
    return __builtin_bit_cast(float, u);
}
// packed RNE f32->bf16 pair: 1 VALU op for 2 elements
static __device__ __forceinline__ unsigned cvt_pk_bf16(float a, float b) {
    unsigned r;
    asm("v_cvt_pk_bf16_f32 %0, %1, %2" : "=v"(r) : "v"(a), "v"(b));
    return r;
}

// One block per chunk: compute GBN stats, then write normalized a as bf16.
__global__ void gbn_norm_kernel(const float* __restrict__ a,
                                const float* __restrict__ gamma,
                                const float* __restrict__ beta,
                                unsigned short* __restrict__ ab) {
    int c = blockIdx.x;
    int j = threadIdx.x;            // feature 0..127
    const float* p = a + (size_t)c * (VBS * NA) + j;
    float s = 0.f, s2 = 0.f;
#pragma unroll 8
    for (int r = 0; r < VBS; ++r) {
        float v = p[r * NA];
        s += v; s2 += v * v;
    }
    float mean = s * (1.f / VBS);
    float var  = fmaxf(s2 * (1.f / VBS) - mean * mean, 0.f);   // biased var
    float sc = gamma[j] * rsqrtf(var + 1e-5f);
    float sh = beta[j] - mean * sc;
    unsigned short* o = ab + (size_t)c * (VBS * NA) + j;
#pragma unroll 8
    for (int r = 0; r < VBS; ++r) {
        float v = p[r * NA];
        o[r * NA] = (unsigned short)f2bf(v * sc + sh);
    }
}

// Pack W: chunk c = ((wv*4+ks)*16+nf)*64 + lane, lane=(g*16+q),
// holding W[wv*256 + nf*16 + q][ks*32 + g*8 .. +8].
__global__ void wpack_kernel(const float* __restrict__ W, u16x8* __restrict__ Wp) {
    int c = blockIdx.x * 256 + threadIdx.x;   // 16384 chunks
    int lane = c & 63;
    int nf   = (c >> 6) & 15;
    int ks   = (c >> 10) & 3;
    int wv   = (c >> 12) & 3;
    int g = lane >> 4, q = lane & 15;
    const float* src = W + (size_t)(wv * 256 + nf * 16 + q) * NA + ks * 32 + g * 8;
    u16x8 h;
#pragma unroll
    for (int i = 0; i < 8; ++i) h[i] = (unsigned short)f2bf(src[i]);
    Wp[c] = h;
}

// R13 structure (passing, 163us) with ONE change: Wp loads split into a
// 16-deep batch (bfr[16]) before the MFMA loop, at launch_bounds(256,2)
// (256-reg budget, so the batch can materialize). Everything else identical.
__global__ __launch_bounds__(256, 2) void fused_kernel(
    const unsigned short* __restrict__ ab,
    const float* __restrict__ prior,
    const u16x8* __restrict__ Wp,
    float* __restrict__ out) {

    const int tid  = threadIdx.x;
    const int wave = tid >> 6;        // 0..3  (N block of 256)
    const int lane = tid & 63;
    const int g    = lane >> 4;       // 0..3
    const int q    = lane & 15;       // output row within tile

    const int r0 = blockIdx.x * 16;

    // ---- prefetch prior into registers (HBM latency overlaps GEMM) ----
    float4 pr[16];
    {
        const float* pb = prior + (size_t)(r0 + q) * D_OUT + wave * 256 + 4 * g;
#pragma unroll
        for (int nf = 0; nf < 16; ++nf) pr[nf] = *(const float4*)(pb + nf * 16);
    }

    f32x4 acc[16];
#pragma unroll
    for (int i = 0; i < 16; ++i) acc[i] = (f32x4){0.f, 0.f, 0.f, 0.f};

    // ---- GEMM: y = GBN(a)[16x128] * W^T; 16-deep B-fragment batches ----
#pragma unroll
    for (int ks = 0; ks < 4; ++ks) {
        const int k0 = ks * 32 + g * 8;
        bf16x8s af = *(const bf16x8s*)(ab + (size_t)(r0 + q) * NA + k0);

        const bf16x8s* wp = (const bf16x8s*)(Wp + ((size_t)(wave * 4 + ks) * 16) * 64 + lane);
        bf16x8s bfr[16];
#pragma unroll
        for (int nf = 0; nf < 16; ++nf) bfr[nf] = wp[nf * 64];
#pragma unroll
        for (int nf = 0; nf < 16; ++nf)
            acc[nf] = __builtin_amdgcn_mfma_f32_16x16x32_bf16(bfr[nf], af, acc[nf], 0, 0, 0);
    }

    // ---- multiply by prior (from registers) ----
#pragma unroll
    for (int nf = 0; nf < 16; ++nf) {
        acc[nf][0] *= pr[nf].x; acc[nf][1] *= pr[nf].y;
        acc[nf][2] *= pr[nf].z; acc[nf][3] *= pr[nf].w;
    }

    // ---- transpose through LDS (bf16, padded layout) ----
    __shared__ unsigned short ls[16][1032];   // 1032 = 1024 + 8 pad, 33 KB
#pragma unroll
    for (int nf = 0; nf < 16; ++nf) {
        uint2 hh;
        hh.x = cvt_pk_bf16(acc[nf][0], acc[nf][1]);
        hh.y = cvt_pk_bf16(acc[nf][2], acc[nf][3]);
        *(uint2*)&ls[q][wave * 256 + nf * 16 + 4 * g] = hh;
    }
    __syncthreads();

    // ---- load this wave's 4 rows as f32x2 pairs: va[4][8] ----
    f32x2 va[4][8];
#pragma unroll
    for (int r = 0; r < 4; ++r) {
        const int row = wave * 4 + r;
#pragma unroll
        for (int j = 0; j < 4; ++j) {
            u16x4 hv = *(const u16x4*)&ls[row][j * 256 + lane * 4];
            va[r][2 * j + 0] = (f32x2){bf2f(hv[0]), bf2f(hv[1])};
            va[r][2 * j + 1] = (f32x2){bf2f(hv[2]), bf2f(hv[3])};
        }
    }

    // ---- row maxima (packed tree + wave reduce) -> tau0 = max - 1 ----
    float mx[4];
#pragma unroll
    for (int r = 0; r < 4; ++r) {
        f32x2 m2 = va[r][0];
#pragma unroll
        for (int e = 1; e < 8; ++e) m2 = __builtin_elementwise_max(m2, va[r][e]);
        mx[r] = fmaxf(m2[0], m2[1]);
    }
#pragma unroll
    for (int m = 1; m < 64; m <<= 1) {
#pragma unroll
        for (int r = 0; r < 4; ++r) mx[r] = fmaxf(mx[r], __shfl_xor(mx[r], m));
    }

    float tau[4];
    int   cp[4];
#pragma unroll
    for (int r = 0; r < 4; ++r) { tau[r] = mx[r] - 1.f; cp[r] = -1; }

    // ---- Michelot from the bracket: tau += (F(tau)-1)/C, monotone up ----
#pragma unroll 1
    for (int it = 0; it < 16; ++it) {
        f32x2 t2[4];
#pragma unroll
        for (int r = 0; r < 4; ++r) t2[r] = (f32x2){tau[r], tau[r]};
        f32x2 S2[4];
        int   C[4];
#pragma unroll
        for (int r = 0; r < 4; ++r) { S2[r] = (f32x2){0.f, 0.f}; C[r] = 0; }
#pragma unroll
        for (int e = 0; e < 8; ++e) {
#pragma unroll
            for (int r = 0; r < 4; ++r) {
                f32x2 d = va[r][e] - t2[r];
                S2[r] += __builtin_elementwise_max(d, (f32x2){0.f, 0.f});
                C[r] += (int)__popcll(__ballot(d[0] > 0.f));
                C[r] += (int)__popcll(__ballot(d[1] > 0.f));
            }
        }
        float S[4];
#pragma unroll
        for (int r = 0; r < 4; ++r) S[r] = S2[r][0] + S2[r][1];
#pragma unroll
        for (int m = 1; m < 64; m <<= 1) {
#pragma unroll
            for (int r = 0; r < 4; ++r) S[r] += __shfl_xor(S[r], m);
        }
        bool all_done = true;
#pragma unroll
        for (int r = 0; r < 4; ++r) {
            tau[r] += (S[r] - 1.f) * __builtin_amdgcn_rcpf((float)C[r]);
            all_done = all_done && (C[r] == cp[r]);
            cp[r] = C[r];
        }
        if (all_done) break;
    }

    // ---- output: reference computes relu(x + tau_std) -> ADD tau ----
#pragma unroll
    for (int r = 0; r < 4; ++r) {
        const int row = wave * 4 + r;
        f32x2 t2 = (f32x2){tau[r], tau[r]};
        float* ob = out + (size_t)(r0 + row) * D_OUT + lane * 4;
#pragma unroll
        for (int j = 0; j < 4; ++j) {
            f32x2 o0 = __builtin_elementwise_max(va[r][2 * j + 0] + t2, (f32x2){0.f, 0.f});
            f32x2 o1 = __builtin_elementwise_max(va[r][2 * j + 1] + t2, (f32x2){0.f, 0.f});
            float4 o;
            o.x = o0[0]; o.y = o0[1]; o.z = o1[0]; o.w = o1[1];
            *(float4*)(ob + j * 256) = o;
        }
    }
}

extern "C" void kernel_launch(void* const* d_in, const int* in_sizes, int n_in,
                              void* d_out, int out_size, void* d_ws, size_t ws_size,
                              hipStream_t stream) {
    const float* a     = (const float*)d_in[0];
    const float* prior = (const float*)d_in[1];
    const float* gamma = (const float*)d_in[2];
    const float* beta  = (const float*)d_in[3];
    const float* W     = (const float*)d_in[4];
    float* out = (float*)d_out;

    u16x8*          Wp = (u16x8*)d_ws;                            // 256 KB @ 0
    unsigned short* ab = (unsigned short*)((char*)d_ws + 262144); // 16 MB @ 256K

    gbn_norm_kernel<<<NCHUNK, VBS, 0, stream>>>(a, gamma, beta, ab);
    wpack_kernel<<<64, 256, 0, stream>>>(W, Wp);
    fused_kernel<<<B_ROWS / 16, 256, 0, stream>>>(ab, prior, Wp, out);
}